// Round 1
// baseline (180.051 us; speedup 1.0000x reference)
//
#include <hip/hip_runtime.h>
#include <hip/hip_bf16.h>
#include <stdint.h>

#define NPAIR 4096
#define N2    8192      // 2N rows
#define DIM   256
// exp(x/T) = exp2(x * log2(e)/T), T=0.5
#define EXP_SCALE 2.8853900817779268f

typedef short bf16x8 __attribute__((ext_vector_type(8)));
typedef float f32x4  __attribute__((ext_vector_type(4)));

static __device__ __forceinline__ unsigned short f2bf(float f) {
    uint32_t u = __float_as_uint(f);
    uint32_t r = (u + 0x7fffu + ((u >> 16) & 1u)) >> 16;
    return (unsigned short)r;
}

static __device__ __forceinline__ void async_copy16(void* lds, const void* g) {
    __builtin_amdgcn_global_load_lds(
        (const __attribute__((address_space(1))) void*)g,
        (__attribute__((address_space(3))) void*)lds, 16, 0, 0);
}

// ---------------- Kernel A: normalize rows + positives dot ----------------
// one wave per pair index i; writes bf16 reps rows i and i+NPAIR, atomicAdds p_i.
__global__ __launch_bounds__(64) void normalize_kernel(
    const float* __restrict__ emb_i, const float* __restrict__ emb_j,
    unsigned short* __restrict__ reps, float* __restrict__ psum) {
    int i = blockIdx.x;
    int l = threadIdx.x;            // 0..63, 4 floats each
    float4 a = ((const float4*)(emb_i + (size_t)i * DIM))[l];
    float4 b = ((const float4*)(emb_j + (size_t)i * DIM))[l];
    float si = a.x*a.x + a.y*a.y + a.z*a.z + a.w*a.w;
    float sj = b.x*b.x + b.y*b.y + b.z*b.z + b.w*b.w;
    float dp = a.x*b.x + a.y*b.y + a.z*b.z + a.w*b.w;
    #pragma unroll
    for (int off = 32; off; off >>= 1) {
        si += __shfl_xor(si, off);
        sj += __shfl_xor(sj, off);
        dp += __shfl_xor(dp, off);
    }
    float ni = fmaxf(sqrtf(si), 1e-12f);
    float nj = fmaxf(sqrtf(sj), 1e-12f);
    float ri = 1.0f / ni, rj = 1.0f / nj;

    ushort4 ua, ub;
    ua.x = f2bf(a.x * ri); ua.y = f2bf(a.y * ri);
    ua.z = f2bf(a.z * ri); ua.w = f2bf(a.w * ri);
    ub.x = f2bf(b.x * rj); ub.y = f2bf(b.y * rj);
    ub.z = f2bf(b.z * rj); ub.w = f2bf(b.w * rj);
    *(ushort4*)(reps + (size_t)i * DIM + l * 4)            = ua;
    *(ushort4*)(reps + (size_t)(i + NPAIR) * DIM + l * 4)  = ub;

    if (l == 0) atomicAdd(psum, dp * ri * rj);
}

// ---------- Kernel B: fused sim-tile GEMM + exp + masked row-sum ----------
// 128x128 output tile, 4 waves (2x2), 16x16x32 bf16 MFMA, BK=32,
// global_load_lds width-16 staging, epilogue reduces exp(sim/T) per row.
__global__ __launch_bounds__(256) void simexp_kernel(
    const unsigned short* __restrict__ reps, float* __restrict__ rowsum) {
    __shared__ unsigned short As[128 * 32];
    __shared__ unsigned short Bs[128 * 32];

    int t = threadIdx.x;
    int l = t & 63;
    int w = t >> 6;
    int wr = w >> 1, wc = w & 1;
    int brow = blockIdx.y * 128;
    int bcol = blockIdx.x * 128;

    f32x4 acc[4][4];
    #pragma unroll
    for (int mi = 0; mi < 4; ++mi)
        #pragma unroll
        for (int ni = 0; ni < 4; ++ni)
            acc[mi][ni] = (f32x4){0.f, 0.f, 0.f, 0.f};

    int frow = l & 15;
    int koff = (l >> 4) * 8;

    for (int kt = 0; kt < DIM; kt += 32) {
        __syncthreads();   // previous iter's ds_reads complete before overwrite
        #pragma unroll
        for (int p = 0; p < 2; ++p) {
            int f  = t * 8 + p * 2048;        // flat bf16 element index in tile
            int r  = f >> 5;
            int kk = f & 31;
            async_copy16(&As[f], reps + (size_t)(brow + r) * DIM + kt + kk);
            async_copy16(&Bs[f], reps + (size_t)(bcol + r) * DIM + kt + kk);
        }
        asm volatile("s_waitcnt vmcnt(0)" ::: "memory");
        __syncthreads();

        bf16x8 bfr[4];
        #pragma unroll
        for (int ni = 0; ni < 4; ++ni)
            bfr[ni] = *(const bf16x8*)&Bs[(wc * 64 + ni * 16 + frow) * 32 + koff];
        #pragma unroll
        for (int mi = 0; mi < 4; ++mi) {
            bf16x8 afr = *(const bf16x8*)&As[(wr * 64 + mi * 16 + frow) * 32 + koff];
            #pragma unroll
            for (int ni = 0; ni < 4; ++ni)
                acc[mi][ni] = __builtin_amdgcn_mfma_f32_16x16x32_bf16(
                    afr, bfr[ni], acc[mi][ni], 0, 0, 0);
        }
    }

    // Epilogue: C/D layout col=lane&15, row=(lane>>4)*4+j  [m89/m91]
    int rbase = brow + wr * 64 + (l >> 4) * 4;
    int cbase = bcol + wc * 64 + (l & 15);
    #pragma unroll
    for (int mi = 0; mi < 4; ++mi) {
        #pragma unroll
        for (int j = 0; j < 4; ++j) {
            int grow = rbase + mi * 16 + j;
            float s = 0.f;
            #pragma unroll
            for (int ni = 0; ni < 4; ++ni) {
                int gcol = cbase + ni * 16;
                float e = exp2f(acc[mi][ni][j] * EXP_SCALE);
                s += (grow == gcol) ? 0.f : e;   // mask diagonal
            }
            // reduce across the 16 lanes holding this row's columns
            s += __shfl_xor(s, 1);
            s += __shfl_xor(s, 2);
            s += __shfl_xor(s, 4);
            s += __shfl_xor(s, 8);
            if ((l & 15) == 0) atomicAdd(&rowsum[grow], s);
        }
    }
}

// ---------------- Kernel C: finalize ----------------
__global__ __launch_bounds__(256) void finalize_kernel(
    const float* __restrict__ rowsum, const float* __restrict__ psum,
    float* __restrict__ out) {
    int t = threadIdx.x;
    float s = 0.f;
    for (int r = t; r < N2; r += 256)
        s += logf(rowsum[r]);
    #pragma unroll
    for (int off = 32; off; off >>= 1) s += __shfl_xor(s, off);
    __shared__ float red[4];
    if ((t & 63) == 0) red[t >> 6] = s;
    __syncthreads();
    if (t == 0) {
        float tot = red[0] + red[1] + red[2] + red[3];
        out[0] = (tot - (2.0f / 0.5f) * psum[0]) / (float)N2;
    }
}

extern "C" void kernel_launch(void* const* d_in, const int* in_sizes, int n_in,
                              void* d_out, int out_size, void* d_ws, size_t ws_size,
                              hipStream_t stream) {
    const float* emb_i = (const float*)d_in[0];
    const float* emb_j = (const float*)d_in[1];
    float* out = (float*)d_out;

    char* ws = (char*)d_ws;
    float*          psum   = (float*)ws;                       // 4 B (padded 256)
    float*          rowsum = (float*)(ws + 256);               // 8192 * 4 B
    unsigned short* reps   = (unsigned short*)(ws + 256 + N2 * 4); // 8192*256*2 B

    hipMemsetAsync(ws, 0, 256 + N2 * 4, stream);

    normalize_kernel<<<NPAIR, 64, 0, stream>>>(emb_i, emb_j, reps, psum);

    dim3 grid(N2 / 128, N2 / 128);
    simexp_kernel<<<grid, 256, 0, stream>>>(reps, rowsum);

    finalize_kernel<<<1, 256, 0, stream>>>(rowsum, psum, out);
}

// Round 2
// 72.242 us; speedup vs baseline: 2.4924x; 2.4924x over previous
//
#include <hip/hip_runtime.h>
#include <hip/hip_bf16.h>
#include <stdint.h>

#define NPAIR 4096
#define N2    8192      // 2N rows
#define DIM   256
#define BK    64
// exp(x/T) = exp2(x * log2(e)/T), T=0.5
#define EXP_SCALE 2.8853900817779268f

typedef short bf16x8 __attribute__((ext_vector_type(8)));
typedef float f32x4  __attribute__((ext_vector_type(4)));

static __device__ __forceinline__ unsigned short f2bf(float f) {
    uint32_t u = __float_as_uint(f);
    uint32_t r = (u + 0x7fffu + ((u >> 16) & 1u)) >> 16;
    return (unsigned short)r;
}

static __device__ __forceinline__ void async_copy16(void* lds, const void* g) {
    __builtin_amdgcn_global_load_lds(
        (const __attribute__((address_space(1))) void*)g,
        (__attribute__((address_space(3))) void*)lds, 16, 0, 0);
}

// ---------------- Kernel A: normalize rows + positive dot + zero rowsum ----
// one wave per pair index i; writes bf16 reps rows i and i+NPAIR,
// stores pdot[i] (NO atomics), zeroes rowsum[2i], rowsum[2i+1].
__global__ __launch_bounds__(64) void normalize_kernel(
    const float* __restrict__ emb_i, const float* __restrict__ emb_j,
    unsigned short* __restrict__ reps, float* __restrict__ pdot,
    float* __restrict__ rowsum) {
    int i = blockIdx.x;
    int l = threadIdx.x;            // 0..63, 4 floats each
    float4 a = ((const float4*)(emb_i + (size_t)i * DIM))[l];
    float4 b = ((const float4*)(emb_j + (size_t)i * DIM))[l];
    float si = a.x*a.x + a.y*a.y + a.z*a.z + a.w*a.w;
    float sj = b.x*b.x + b.y*b.y + b.z*b.z + b.w*b.w;
    float dp = a.x*b.x + a.y*b.y + a.z*b.z + a.w*b.w;
    #pragma unroll
    for (int off = 32; off; off >>= 1) {
        si += __shfl_xor(si, off);
        sj += __shfl_xor(sj, off);
        dp += __shfl_xor(dp, off);
    }
    float ri = 1.0f / fmaxf(sqrtf(si), 1e-12f);
    float rj = 1.0f / fmaxf(sqrtf(sj), 1e-12f);

    ushort4 ua, ub;
    ua.x = f2bf(a.x * ri); ua.y = f2bf(a.y * ri);
    ua.z = f2bf(a.z * ri); ua.w = f2bf(a.w * ri);
    ub.x = f2bf(b.x * rj); ub.y = f2bf(b.y * rj);
    ub.z = f2bf(b.z * rj); ub.w = f2bf(b.w * rj);
    *(ushort4*)(reps + (size_t)i * DIM + l * 4)            = ua;
    *(ushort4*)(reps + (size_t)(i + NPAIR) * DIM + l * 4)  = ub;

    if (l == 0) pdot[i] = dp * ri * rj;
    if (l < 2)  rowsum[2 * i + l] = 0.f;
}

// ---------- Kernel B: fused sim-tile GEMM + exp + masked column-sum -------
// 128x128 tile, 4 waves (2x2), 16x16x32 bf16 MFMA, BK=64.
// LDS rows are 128B; XOR swizzle (slot ^= row&7) applied BOTH sides:
// pre-swizzled global source for global_load_lds (LDS dest stays linear)
// and swizzled ds_read address. -> conflict-free b128 reads.
// Epilogue: exp(sim/T) is symmetric over the full grid, so per-block
// COLUMN sums accumulate the same total as row sums: lane-local partials,
// 2 shuffles per column, atomics only from lanes 0..15.
__global__ __launch_bounds__(256) void simexp_kernel(
    const unsigned short* __restrict__ reps, float* __restrict__ rowsum) {
    __shared__ unsigned short As[128 * BK];
    __shared__ unsigned short Bs[128 * BK];

    int t = threadIdx.x;
    int l = t & 63;
    int w = t >> 6;
    int wr = w >> 1, wc = w & 1;
    int brow = blockIdx.y * 128;
    int bcol = blockIdx.x * 128;

    f32x4 acc[4][4];
    #pragma unroll
    for (int mi = 0; mi < 4; ++mi)
        #pragma unroll
        for (int ni = 0; ni < 4; ++ni)
            acc[mi][ni] = (f32x4){0.f, 0.f, 0.f, 0.f};

    int frow = l & 15;
    int k16  = l >> 4;          // 0..3

    for (int kt = 0; kt < DIM; kt += BK) {
        __syncthreads();   // previous iter's ds_reads complete before overwrite
        #pragma unroll
        for (int p = 0; p < 4; ++p) {
            int f16  = t + p * 256;       // 16B-chunk index, 0..1023
            int r    = f16 >> 3;          // tile row (8 chunks per 128B row)
            int slot = f16 & 7;           // 16B slot within row
            int gk   = (slot ^ (r & 7)) * 8;   // pre-swizzled global k-chunk
            async_copy16(&As[f16 * 8], reps + (size_t)(brow + r) * DIM + kt + gk);
            async_copy16(&Bs[f16 * 8], reps + (size_t)(bcol + r) * DIM + kt + gk);
        }
        asm volatile("s_waitcnt vmcnt(0)" ::: "memory");
        __syncthreads();

        #pragma unroll
        for (int kk = 0; kk < 2; ++kk) {
            bf16x8 afr[4], bfr[4];
            #pragma unroll
            for (int ni = 0; ni < 4; ++ni) {
                int r    = wc * 64 + ni * 16 + frow;
                int slot = (kk * 4 + k16) ^ (r & 7);
                bfr[ni] = *(const bf16x8*)&Bs[r * BK + slot * 8];
            }
            #pragma unroll
            for (int mi = 0; mi < 4; ++mi) {
                int r    = wr * 64 + mi * 16 + frow;
                int slot = (kk * 4 + k16) ^ (r & 7);
                afr[mi] = *(const bf16x8*)&As[r * BK + slot * 8];
            }
            #pragma unroll
            for (int mi = 0; mi < 4; ++mi)
                #pragma unroll
                for (int ni = 0; ni < 4; ++ni)
                    acc[mi][ni] = __builtin_amdgcn_mfma_f32_16x16x32_bf16(
                        afr[mi], bfr[ni], acc[mi][ni], 0, 0, 0);
        }
    }

    // Epilogue: C/D layout col=lane&15, row=(lane>>4)*4+j  [m89/m91]
    int rbase = brow + wr * 64 + k16 * 4;
    int cb    = bcol + wc * 64 + frow;
    float csum[4] = {0.f, 0.f, 0.f, 0.f};
    #pragma unroll
    for (int mi = 0; mi < 4; ++mi) {
        #pragma unroll
        for (int j = 0; j < 4; ++j) {
            int grow = rbase + mi * 16 + j;
            #pragma unroll
            for (int ni = 0; ni < 4; ++ni) {
                float e = exp2f(acc[mi][ni][j] * EXP_SCALE);
                csum[ni] += (grow == cb + ni * 16) ? 0.f : e;  // mask diagonal
            }
        }
    }
    #pragma unroll
    for (int ni = 0; ni < 4; ++ni) {
        csum[ni] += __shfl_xor(csum[ni], 16);
        csum[ni] += __shfl_xor(csum[ni], 32);
    }
    if (l < 16) {
        #pragma unroll
        for (int ni = 0; ni < 4; ++ni)
            atomicAdd(&rowsum[cb + ni * 16], csum[ni]);
    }
}

// ---------------- Kernel C: finalize ----------------
__global__ __launch_bounds__(256) void finalize_kernel(
    const float* __restrict__ rowsum, const float* __restrict__ pdot,
    float* __restrict__ out) {
    int t = threadIdx.x;
    float s = 0.f, p = 0.f;
    for (int r = t; r < N2; r += 256)    s += logf(rowsum[r]);
    for (int r = t; r < NPAIR; r += 256) p += pdot[r];
    #pragma unroll
    for (int off = 32; off; off >>= 1) {
        s += __shfl_xor(s, off);
        p += __shfl_xor(p, off);
    }
    __shared__ float reds[4], redp[4];
    if ((t & 63) == 0) { reds[t >> 6] = s; redp[t >> 6] = p; }
    __syncthreads();
    if (t == 0) {
        float S = reds[0] + reds[1] + reds[2] + reds[3];
        float P = redp[0] + redp[1] + redp[2] + redp[3];
        // loss = (sum log D - (2/T) * 2 * sum(dp)) / 2N, 2/T = 4 applied to P
        out[0] = (S - 4.0f * P) / (float)N2;
    }
}

extern "C" void kernel_launch(void* const* d_in, const int* in_sizes, int n_in,
                              void* d_out, int out_size, void* d_ws, size_t ws_size,
                              hipStream_t stream) {
    const float* emb_i = (const float*)d_in[0];
    const float* emb_j = (const float*)d_in[1];
    float* out = (float*)d_out;

    char* ws = (char*)d_ws;
    float*          rowsum = (float*)ws;                 // 8192 * 4 B
    float*          pdot   = (float*)(ws + 32768);       // 4096 * 4 B
    unsigned short* reps   = (unsigned short*)(ws + 65536); // 8192*256*2 B

    normalize_kernel<<<NPAIR, 64, 0, stream>>>(emb_i, emb_j, reps, pdot, rowsum);

    dim3 grid(N2 / 128, N2 / 128);
    simexp_kernel<<<grid, 256, 0, stream>>>(reps, rowsum);

    finalize_kernel<<<1, 256, 0, stream>>>(rowsum, pdot, out);
}